// Round 14
// baseline (105.986 us; speedup 1.0000x reference)
//
#include <hip/hip_runtime.h>
#include <hip/hip_fp16.h>

#define B_   512
#define F_   2048
#define K_   64
#define D_   16
#define N_   1024
#define OUTW (F_+K_)    // 2112
#define LOG2E 1.44269504088896340736f
#define KSPLIT 4
#define KCH  (F_/KSPLIT)   // 512
#define BK   64
#define NSTEP (KCH/BK)     // 8
#define KBD  (K_*B_*D_)    // 524288

typedef __attribute__((ext_vector_type(8))) short short8;
typedef __attribute__((ext_vector_type(4))) float f32x4;

__device__ __forceinline__ ushort f2bf(float f) {
    union { float f; unsigned u; } un; un.f = f;
    unsigned u = un.u;
    u += 0x7FFF + ((u >> 16) & 1);   // RNE
    return (ushort)(u >> 16);
}
__device__ __forceinline__ uint f2bf2(float lo, float hi) {
    return (uint)f2bf(lo) | ((uint)f2bf(hi) << 16);
}
// exp2 via raw v_exp_f32, negation folded into the input modifier
__device__ __forceinline__ float exp2_neg(float x) {
    float r;
    asm("v_exp_f32 %0, -%1" : "=v"(r) : "v"(x));
    return r;
}

// ---- prep_w: wt[n][f] = bf16(W[f][n]); 256 blocks x 8 32x32 tiles ----
__global__ __launch_bounds__(256) void prep_w_kernel(const float* __restrict__ w,
                                                     ushort* __restrict__ wt) {
    __shared__ float t[32][33];
    const int tid = threadIdx.x;
    const int r  = tid >> 3;           // 0..31
    const int c4 = (tid & 7) * 4;      // 0..28
    #pragma unroll 1
    for (int i = 0; i < 8; ++i) {
        const int tb = blockIdx.x * 8 + i;       // 0..2047
        const int f0 = (tb >> 5) * 32, n0 = (tb & 31) * 32;
        float4 v = *(const float4*)(w + (size_t)(f0 + r) * N_ + n0 + c4);
        __syncthreads();
        t[r][c4 + 0] = v.x; t[r][c4 + 1] = v.y;
        t[r][c4 + 2] = v.z; t[r][c4 + 3] = v.w;
        __syncthreads();
        ushort4 u = make_ushort4(f2bf(t[c4 + 0][r]), f2bf(t[c4 + 1][r]),
                                 f2bf(t[c4 + 2][r]), f2bf(t[c4 + 3][r]));
        *(ushort4*)(wt + (size_t)(n0 + r) * F_ + f0 + c4) = u;
    }
}

// ---- gemm_fused: A staged from x f32 (inline bf16*log2e convert + piggyback
//      out[:, :2048]=x copy on by==0 blocks), B staged from wt (r13 pattern),
//      LDS double-buffer XOR-swizzled, split-K=4 partial stores (no atomics).
__global__ __launch_bounds__(256) void gemm_fused_kernel(const float* __restrict__ x,
                                                         const ushort* __restrict__ wt,
                                                         float* __restrict__ out,
                                                         float* __restrict__ actp) {
    __shared__ ushort As[2][64 * 64];   // 8KB per buf
    __shared__ ushort Bs[2][64 * 64];

    // XCD-swizzled decode: 512 blocks, 64 contiguous per XCD
    const int flat = blockIdx.x;
    const int wg = (flat & 7) * 64 + (flat >> 3);
    const int bx = wg & 7, by = (wg >> 3) & 15, bz = wg >> 7;
    const int bm0 = bx * 64, bn0 = by * 64, f0 = bz * KCH;

    const int tid = threadIdx.x;
    const int l = tid & 63, wv = tid >> 6;
    const int mw = (wv >> 1) * 32, nw = (wv & 1) * 32;
    const int lr = l & 15, lkc = l >> 4, sw = lr & 7;

    // A staging: thread = (row ar, 16-f group acg)
    const int ar = tid >> 2, acg = tid & 3;
    const f32x4* gA = (const f32x4*)(x + (size_t)(bm0 + ar) * F_ + f0) + acg * 4;
    float* oA = out + (size_t)(bm0 + ar) * OUTW + f0 + acg * 16;
    const int wa0 = ar * 64 + (((acg * 2)     ^ (ar & 7)) * 8);
    const int wa1 = ar * 64 + (((acg * 2 + 1) ^ (ar & 7)) * 8);
    // B staging: thread = (row ar, chunk pair c0) reading wt rows (bf16, coalesced)
    const int c0 = (tid & 3) * 2;
    const ushort* gB0 = wt + (size_t)(bn0 + ar) * F_ + f0 + c0 * 8;
    const ushort* gB1 = gB0 + 8;
    const int wb0 = ar * 64 + ((c0       ^ (ar & 7)) * 8);
    const int wb1 = ar * 64 + (((c0 + 1) ^ (ar & 7)) * 8);

    f32x4 a0r = gA[0], a1r = gA[1], a2r = gA[2], a3r = gA[3];
    uint4 b0v = *(const uint4*)gB0;
    uint4 b1v = *(const uint4*)gB1;

    f32x4 acc00 = {}, acc01 = {}, acc10 = {}, acc11 = {};

    // prologue: stage s=0
    {
        uint4 ca = make_uint4(f2bf2(a0r[0]*LOG2E, a0r[1]*LOG2E), f2bf2(a0r[2]*LOG2E, a0r[3]*LOG2E),
                              f2bf2(a1r[0]*LOG2E, a1r[1]*LOG2E), f2bf2(a1r[2]*LOG2E, a1r[3]*LOG2E));
        uint4 cb = make_uint4(f2bf2(a2r[0]*LOG2E, a2r[1]*LOG2E), f2bf2(a2r[2]*LOG2E, a2r[3]*LOG2E),
                              f2bf2(a3r[0]*LOG2E, a3r[1]*LOG2E), f2bf2(a3r[2]*LOG2E, a3r[3]*LOG2E));
        *(uint4*)&As[0][wa0] = ca;  *(uint4*)&As[0][wa1] = cb;
        *(uint4*)&Bs[0][wb0] = b0v; *(uint4*)&Bs[0][wb1] = b1v;
        if (by == 0) {
            *(f32x4*)(oA + 0)  = a0r; *(f32x4*)(oA + 4)  = a1r;
            *(f32x4*)(oA + 8)  = a2r; *(f32x4*)(oA + 12) = a3r;
        }
    }
    __syncthreads();

    #pragma unroll
    for (int s = 0; s < NSTEP; ++s) {
        const int cur = s & 1;
        if (s < NSTEP - 1) {   // issue next-step loads (hide under MFMA)
            a0r = gA[(s + 1) * 16 + 0]; a1r = gA[(s + 1) * 16 + 1];
            a2r = gA[(s + 1) * 16 + 2]; a3r = gA[(s + 1) * 16 + 3];
            b0v = *(const uint4*)(gB0 + (s + 1) * BK);
            b1v = *(const uint4*)(gB1 + (s + 1) * BK);
        }
        #pragma unroll
        for (int ks = 0; ks < 2; ++ks) {
            const int cb_ = ks * 4 + lkc;
            short8 A0 = *(const short8*)&As[cur][(mw + lr) * 64      + ((cb_ ^ sw) * 8)];
            short8 A1 = *(const short8*)&As[cur][(mw + 16 + lr) * 64 + ((cb_ ^ sw) * 8)];
            short8 B0 = *(const short8*)&Bs[cur][(nw + lr) * 64      + ((cb_ ^ sw) * 8)];
            short8 B1 = *(const short8*)&Bs[cur][(nw + 16 + lr) * 64 + ((cb_ ^ sw) * 8)];
            acc00 = __builtin_amdgcn_mfma_f32_16x16x32_bf16(A0, B0, acc00, 0, 0, 0);
            acc01 = __builtin_amdgcn_mfma_f32_16x16x32_bf16(A0, B1, acc01, 0, 0, 0);
            acc10 = __builtin_amdgcn_mfma_f32_16x16x32_bf16(A1, B0, acc10, 0, 0, 0);
            acc11 = __builtin_amdgcn_mfma_f32_16x16x32_bf16(A1, B1, acc11, 0, 0, 0);
        }
        if (s < NSTEP - 1) {
            const int nxt = cur ^ 1;
            uint4 ca = make_uint4(f2bf2(a0r[0]*LOG2E, a0r[1]*LOG2E), f2bf2(a0r[2]*LOG2E, a0r[3]*LOG2E),
                                  f2bf2(a1r[0]*LOG2E, a1r[1]*LOG2E), f2bf2(a1r[2]*LOG2E, a1r[3]*LOG2E));
            uint4 cb = make_uint4(f2bf2(a2r[0]*LOG2E, a2r[1]*LOG2E), f2bf2(a2r[2]*LOG2E, a2r[3]*LOG2E),
                                  f2bf2(a3r[0]*LOG2E, a3r[1]*LOG2E), f2bf2(a3r[2]*LOG2E, a3r[3]*LOG2E));
            *(uint4*)&As[nxt][wa0] = ca;  *(uint4*)&As[nxt][wa1] = cb;
            *(uint4*)&Bs[nxt][wb0] = b0v; *(uint4*)&Bs[nxt][wb1] = b1v;
            if (by == 0) {
                float* o = oA + (s + 1) * BK;
                *(f32x4*)(o + 0) = a0r; *(f32x4*)(o + 4)  = a1r;
                *(f32x4*)(o + 8) = a2r; *(f32x4*)(o + 12) = a3r;
            }
        }
        __syncthreads();
    }

    // epilogue: partial stores (no atomics). D layout: col=l&15 (n), row=(l>>4)*4+reg (m)
    float* base = actp + (size_t)bz * KBD;
    #pragma unroll
    for (int mi = 0; mi < 2; ++mi) {
        #pragma unroll
        for (int ni = 0; ni < 2; ++ni) {
            const f32x4 a = (mi == 0) ? (ni == 0 ? acc00 : acc01)
                                      : (ni == 0 ? acc10 : acc11);
            const int n = bn0 + nw + ni * 16 + lr;
            const int k = n >> 4, d = n & 15;
            const int mb = bm0 + mw + mi * 16 + lkc * 4;
            float* dst = base + ((size_t)k * B_ + mb) * D_ + d;
            #pragma unroll
            for (int r2 = 0; r2 < 4; ++r2)
                dst[r2 * D_] = a[r2];
        }
    }
}

// ---- pairwise: sum 4 partials during f16 staging, packed-half2 math ----
__global__ __launch_bounds__(512) void pairwise_kernel(const float* __restrict__ actp,
                                                       float* __restrict__ out) {
    __shared__ __half2 s2[B_ * D_ / 2];   // 16 KB
    __shared__ float red[8][64];

    const int bt = blockIdx.x;    // 8
    const int k  = blockIdx.y;    // 64
    const int tid  = threadIdx.x;
    const int lane = tid & 63;
    const int wave = tid >> 6;

    const f32x4* p0 = (const f32x4*)(actp + (size_t)k * (B_ * D_));
    const f32x4* p1 = p0 + KBD / 4;
    const f32x4* p2 = p1 + KBD / 4;
    const f32x4* p3 = p2 + KBD / 4;
    #pragma unroll
    for (int i = 0; i < 4; ++i) {
        const int idx = tid + i * 512;
        f32x4 v = (p0[idx] + p1[idx]) + (p2[idx] + p3[idx]);
        s2[idx * 2]     = __floats2half2_rn(v[0], v[1]);
        s2[idx * 2 + 1] = __floats2half2_rn(v[2], v[3]);
    }
    // own row (same summation + rounding path => self-pair dist exactly 0)
    const int b = bt * 64 + lane;
    __half2 arr[8];
    #pragma unroll
    for (int i = 0; i < 4; ++i) {
        const int idx = b * 4 + i;
        f32x4 v = (p0[idx] + p1[idx]) + (p2[idx] + p3[idx]);
        arr[i * 2]     = __floats2half2_rn(v[0], v[1]);
        arr[i * 2 + 1] = __floats2half2_rn(v[2], v[3]);
    }
    __syncthreads();

    float p = 0.0f;
    const int b2lo = wave * 64;
    #pragma unroll 4
    for (int b2 = b2lo; b2 < b2lo + 64; ++b2) {
        const __half2* vr = &s2[b2 * 8];   // 32B broadcast: 2x ds_read_b128
        __half2 sA = __habs2(__hsub2(arr[0], vr[0]));
        __half2 sB = __habs2(__hsub2(arr[1], vr[1]));
        sA = __hadd2(sA, __habs2(__hsub2(arr[2], vr[2])));
        sB = __hadd2(sB, __habs2(__hsub2(arr[3], vr[3])));
        sA = __hadd2(sA, __habs2(__hsub2(arr[4], vr[4])));
        sB = __hadd2(sB, __habs2(__hsub2(arr[5], vr[5])));
        sA = __hadd2(sA, __habs2(__hsub2(arr[6], vr[6])));
        sB = __hadd2(sB, __habs2(__hsub2(arr[7], vr[7])));
        sA = __hadd2(sA, sB);
        const float dist = __low2float(sA) + __high2float(sA);
        p += exp2_neg(dist);
    }

    red[wave][lane] = p;
    __syncthreads();
    if (wave == 0) {
        float total = 0.0f;
        #pragma unroll
        for (int i = 0; i < 8; ++i) total += red[i][lane];
        out[(size_t)b * OUTW + F_ + k] = total;
    }
}

extern "C" void kernel_launch(void* const* d_in, const int* in_sizes, int n_in,
                              void* d_out, int out_size, void* d_ws, size_t ws_size,
                              hipStream_t stream) {
    const float* x = (const float*)d_in[0];
    const float* wsrc = (const float*)d_in[1];
    float* out = (float*)d_out;

    // ws: wt bf16 [1024][2048] (4MB) | actp f32 [4][64][512][16] (8MB)
    ushort* wt   = (ushort*)d_ws;
    float*  actp = (float*)((char*)d_ws + (size_t)4 * 1024 * 1024);

    prep_w_kernel<<<256, 256, 0, stream>>>(wsrc, wt);
    gemm_fused_kernel<<<512, 256, 0, stream>>>(x, wt, out, actp);
    pairwise_kernel<<<dim3(8, K_), 512, 0, stream>>>(actp, out);
}